// Round 6
// baseline (729.024 us; speedup 1.0000x reference)
//
#include <hip/hip_runtime.h>
#include <hip/hip_bf16.h>
#include <math.h>

typedef unsigned int uint;
typedef unsigned short ushort;
typedef __attribute__((ext_vector_type(8))) short bf16x8;
typedef __attribute__((ext_vector_type(4))) float f32x4;

__device__ __forceinline__ float bu2f(ushort u){ union{uint u; float f;} v; v.u = ((uint)u)<<16; return v.f; }
__device__ __forceinline__ ushort f2bu(float x){ union{float f; uint u;} v; v.f = x; uint r = (v.u + 0x7FFFu + ((v.u>>16)&1u))>>16; return (ushort)r; }
__device__ __forceinline__ uint pack2(float a, float b){ return (uint)f2bu(a) | ((uint)f2bu(b) << 16); }

#define GEPI_IS0  0
#define GEPI_KV   1
#define GEPI_Q    2
#define GEPI_RELU 3
#define GEPI_MLP2 4
#define GEPI_OUT  5

// C[M,N] = A[M,K(lda)] @ Bt[N,K]^T + bias. bf16 MFMA 16x16x32, tile 128x128x32,
// register-prefetch pipelined K-loop. SWZ: flat grid, XCD-swizzled (4 col-tiles).
template<int EPI, bool SWZ>
__global__ __launch_bounds__(256) void mfma_gemm(
    const ushort* __restrict__ Abf, int lda,
    const ushort* __restrict__ Bt,
    const float* __restrict__ xb0, const float* __restrict__ xb1,
    float* __restrict__ fp0,
    ushort* __restrict__ up0, ushort* __restrict__ up1,
    int M, int N, int K)
{
    __shared__ ushort As[128 * 40];   // +8 bf16 pad per row
    __shared__ ushort Bs[128 * 40];
    int tid  = threadIdx.x;
    int wave = tid >> 6, lane = tid & 63;
    int wr = wave >> 1, wc = wave & 1;
    int quad = lane >> 4, l15 = lane & 15;
    int bx, by;
    if (SWZ) {  // all 4 col-tiles of a row-strip -> same XCD (g%8 dispatch)
        int g = blockIdx.x;
        by = (g & 7) | ((g >> 5) << 3);
        bx = (g >> 3) & 3;
    } else { bx = blockIdx.x; by = blockIdx.y; }
    int row0 = by * 128, col0 = bx * 128;
    int sr = tid >> 1, sc = (tid & 1) * 16;

    f32x4 acc[4][4];
    #pragma unroll
    for (int i = 0; i < 4; i++)
        #pragma unroll
        for (int j = 0; j < 4; j++) acc[i][j] = (f32x4){0.f, 0.f, 0.f, 0.f};

    const ushort* Ap = Abf + (size_t)(row0 + sr) * lda + sc;
    const ushort* Bp = Bt  + (size_t)(col0 + sr) * K   + sc;

    uint4 rg[4];
    rg[0] = *(const uint4*)Ap;       rg[1] = *(const uint4*)(Ap + 8);
    rg[2] = *(const uint4*)Bp;       rg[3] = *(const uint4*)(Bp + 8);

    for (int k0 = 0; k0 < K; k0 += 32) {
        *(uint4*)&As[sr * 40 + sc]     = rg[0];
        *(uint4*)&As[sr * 40 + sc + 8] = rg[1];
        *(uint4*)&Bs[sr * 40 + sc]     = rg[2];
        *(uint4*)&Bs[sr * 40 + sc + 8] = rg[3];
        __syncthreads();
        if (k0 + 32 < K) {   // prefetch next tile; overlaps ds_read+MFMA below
            rg[0] = *(const uint4*)(Ap + k0 + 32);
            rg[1] = *(const uint4*)(Ap + k0 + 40);
            rg[2] = *(const uint4*)(Bp + k0 + 32);
            rg[3] = *(const uint4*)(Bp + k0 + 40);
        }
        bf16x8 af[4], bfr[4];
        #pragma unroll
        for (int mt = 0; mt < 4; mt++)
            af[mt] = *(const bf16x8*)&As[(wr * 64 + mt * 16 + l15) * 40 + quad * 8];
        #pragma unroll
        for (int nt = 0; nt < 4; nt++)
            bfr[nt] = *(const bf16x8*)&Bs[(wc * 64 + nt * 16 + l15) * 40 + quad * 8];
        #pragma unroll
        for (int mt = 0; mt < 4; mt++)
            #pragma unroll
            for (int nt = 0; nt < 4; nt++)
                acc[mt][nt] = __builtin_amdgcn_mfma_f32_16x16x32_bf16(
                    af[mt], bfr[nt], acc[mt][nt], 0, 0, 0);
        __syncthreads();
    }

    #pragma unroll
    for (int mt = 0; mt < 4; mt++) {
        #pragma unroll
        for (int nt = 0; nt < 4; nt++) {
            #pragma unroll
            for (int reg = 0; reg < 4; reg++) {
                int gr = row0 + wr * 64 + mt * 16 + quad * 4 + reg;
                int gc = col0 + wc * 64 + nt * 16 + l15;
                float x = acc[mt][nt][reg];
                if (EPI == GEPI_IS0) {
                    // gr = (n,b) row, gc in [0,2048): slot j=gc>>8, dim=gc&255
                    x += xb0[gc];
                    size_t srow = (size_t)gr * 8 + (gc >> 8);
                    int dim = gc & 255;
                    fp0[srow * 256 + dim] = x;                    // slots f32
                    ushort xb = f2bu(x);
                    up0[srow * 512 + dim]       = xb;             // catb is0 half
                    up0[srow * 512 + 256 + dim] = xb;             // catb slot half
                } else if (EPI == GEPI_KV) {
                    if (gc < 256) {
                        x += xb0[gc];
                        x = x > 0.f ? x + 1.f : expf(x);
                        up0[(size_t)gr * 256 + gc] = f2bu(x);     // kbuf
                    } else {
                        x += xb1[gc - 256];
                        up1[(size_t)gr * 256 + gc - 256] = f2bu(x); // vbuf
                    }
                } else if (EPI == GEPI_Q) {
                    x += xb0[gc];
                    float y = (x + bu2f(up1[(size_t)gr * 512 + gc])) * 0.0625f;
                    y = y > 0.f ? y + 1.f : expf(y);
                    up0[(size_t)gr * 256 + gc] = f2bu(y);         // qbuf bf16
                } else if (EPI == GEPI_RELU) {
                    x += xb0[gc];
                    up0[(size_t)gr * 512 + gc] = f2bu(fmaxf(x, 0.f)); // hbuf
                } else if (EPI == GEPI_MLP2) {
                    x += xb0[gc];
                    size_t i = (size_t)gr * 256 + gc;
                    float s = fp0[i] + x * (1.f / 256.f);
                    fp0[i] = s;                                   // slots f32
                    up0[(size_t)gr * 512 + 256 + gc] = f2bu(s);   // catb slot half
                } else {  // GEPI_OUT
                    x += xb0[gc];
                    fp0[(size_t)gr * 256 + gc] = x;               // out f32
                }
            }
        }
    }
}

// One-shot conversion: sentence->bf16 (vec4), sent_sum->bf16 (vec4),
// weights f32 -> bf16 transposed [N][K].
__global__ __launch_bounds__(256) void prep_kernel(
    const float* __restrict__ sentence, const float* __restrict__ sent_sum,
    const float* __restrict__ Wbind, const float* __restrict__ Wk,
    const float* __restrict__ Wv, const float* __restrict__ Wq,
    const float* __restrict__ W1, const float* __restrict__ W2,
    const float* __restrict__ Wproj,
    ushort* __restrict__ sent_bf, ushort* __restrict__ ssum_bf,
    ushort* __restrict__ Wbind_t, ushort* __restrict__ Wkv_t,
    ushort* __restrict__ Wq_t, ushort* __restrict__ W1_t,
    ushort* __restrict__ W2_t, ushort* __restrict__ Wproj_t)
{
    int gid = blockIdx.x * 256 + threadIdx.x;
    if (gid < 6291456) {           // sentence: 25,165,824 f32 as vec4
        float4 f = ((const float4*)sentence)[gid];
        uint2 o; o.x = pack2(f.x, f.y); o.y = pack2(f.z, f.w);
        ((uint2*)sent_bf)[gid] = o; return;
    }
    gid -= 6291456;
    if (gid < 262144) {            // sent_sum: 1,048,576 f32 as vec4
        float4 f = ((const float4*)sent_sum)[gid];
        uint2 o; o.x = pack2(f.x, f.y); o.y = pack2(f.z, f.w);
        ((uint2*)ssum_bf)[gid] = o; return;
    }
    gid -= 262144;
    int idx = gid;
    if (idx < 1048576) { int n = idx >> 9, k = idx & 511;
        Wbind_t[idx] = f2bu(Wbind[(size_t)k * 2048 + n]); return; }
    idx -= 1048576;
    if (idx < 262144) { int n = idx >> 9, k = idx & 511;
        Wkv_t[idx] = f2bu(n < 256 ? Wk[(size_t)k * 256 + n] : Wv[(size_t)k * 256 + n - 256]); return; }
    idx -= 262144;
    if (idx < 65536) { int n = idx >> 8, k = idx & 255;
        Wq_t[idx] = f2bu(Wq[(size_t)k * 256 + n]); return; }
    idx -= 65536;
    if (idx < 131072) { int n = idx >> 8, k = idx & 255;
        W1_t[idx] = f2bu(W1[(size_t)k * 512 + n]); return; }
    idx -= 131072;
    if (idx < 131072) { int n = idx >> 9, k = idx & 511;
        W2_t[idx] = f2bu(W2[(size_t)k * 256 + n]); return; }
    idx -= 131072;
    if (idx < 131072) { int n = idx >> 9, k = idx & 511;
        Wproj_t[idx] = f2bu(Wproj[(size_t)k * 256 + n]); return; }
}

// Per-(n,b): logits -> softmax(+eps) -> word renorm -> update -> LayerNorm -> ubuf bf16.
__global__ __launch_bounds__(256) void attn_kernel(
    const ushort* __restrict__ kbuf, const ushort* __restrict__ vbuf,
    const ushort* __restrict__ qbuf, const int* __restrict__ mask,
    const float* __restrict__ g_ln, const float* __restrict__ b_ln,
    ushort* __restrict__ ubuf)
{
    const int W = 24, S = 8;
    __shared__ ushort kk[24 * 256], vv[24 * 256];
    __shared__ float qs[8 * 257], us[8 * 257];
    __shared__ float attnw[24][8];
    __shared__ float colsum[8], mean_s[8], rstd_s[8], maskf[24];

    int nb = blockIdx.x, t = threadIdx.x;
    size_t bw = (size_t)nb * W * 256, bs = (size_t)nb * S * 256;

    for (int l = t; l < 3072; l += 256) {
        ((uint*)kk)[l] = ((const uint*)(kbuf + bw))[l];
        ((uint*)vv)[l] = ((const uint*)(vbuf + bw))[l];
    }
    for (int l = t; l < 2048; l += 256)
        qs[(l >> 8) * 257 + (l & 255)] = bu2f(qbuf[bs + l]);
    if (t < W) maskf[t] = mask[(size_t)nb * W + t] ? 0.f : -1e6f;
    __syncthreads();

    if (t < W * S) {
        int i = t >> 3, j = t & 7;
        float a = 0.f;
        #pragma unroll 8
        for (int d = 0; d < 256; d++) a += bu2f(kk[i * 256 + d]) * qs[j * 257 + d];
        attnw[i][j] = a + maskf[i];
    }
    __syncthreads();

    if (t < W) {
        float m = attnw[t][0];
        #pragma unroll
        for (int j = 1; j < S; j++) m = fmaxf(m, attnw[t][j]);
        float e[S]; float s = 0.f;
        #pragma unroll
        for (int j = 0; j < S; j++) { e[j] = expf(attnw[t][j] - m); s += e[j]; }
        #pragma unroll
        for (int j = 0; j < S; j++) attnw[t][j] = e[j] / s + 1e-6f;
    }
    __syncthreads();

    if (t < S) {
        float s = 0.f;
        for (int i = 0; i < W; i++) s += attnw[i][t];
        colsum[t] = s;
    }
    __syncthreads();

    {
        float acc[S] = {};
        #pragma unroll
        for (int i = 0; i < W; i++) {
            float vx = bu2f(vv[i * 256 + t]);
            #pragma unroll
            for (int j = 0; j < S; j++) acc[j] += attnw[i][j] * vx;
        }
        #pragma unroll
        for (int j = 0; j < S; j++) us[j * 257 + t] = acc[j] / colsum[j];
    }
    __syncthreads();

    {
        int lane = t & 63;
        #pragma unroll
        for (int jj = 0; jj < 2; jj++) {
            int j = (t >> 6) * 2 + jj;
            float x0 = us[j * 257 + lane],       x1 = us[j * 257 + lane + 64];
            float x2 = us[j * 257 + lane + 128], x3 = us[j * 257 + lane + 192];
            float p = x0 + x1 + x2 + x3;
            for (int off = 32; off; off >>= 1) p += __shfl_xor(p, off);
            float mean = p * (1.f / 256.f);
            float d0 = x0 - mean, d1 = x1 - mean, d2 = x2 - mean, d3 = x3 - mean;
            float vr = d0 * d0 + d1 * d1 + d2 * d2 + d3 * d3;
            for (int off = 32; off; off >>= 1) vr += __shfl_xor(vr, off);
            if (lane == 0) {
                mean_s[j] = mean;
                rstd_s[j] = rsqrtf(vr * (1.f / 256.f) + 1e-5f);
            }
        }
    }
    __syncthreads();

    {
        float g = g_ln[t], bb = b_ln[t];
        #pragma unroll
        for (int j = 0; j < S; j++)
            ubuf[bs + j * 256 + t] = f2bu((us[j * 257 + t] - mean_s[j]) * rstd_s[j] * g + bb);
    }
}

// ---------------- fallback: round-4 proven mega-kernel (f32 inputs) ----------------
__global__ __launch_bounds__(256) void mega_kernel(
    const float* __restrict__ sentence, const float* __restrict__ sent_sum,
    const int*  __restrict__ mask,
    const float* __restrict__ Wk, const float* __restrict__ bk,
    const float* __restrict__ Wv, const float* __restrict__ bv,
    const float* __restrict__ Wq, const float* __restrict__ bq,
    const float* __restrict__ g_ln, const float* __restrict__ b_ln,
    const float* __restrict__ W1, const float* __restrict__ b1,
    const float* __restrict__ W2, const float* __restrict__ b2,
    const float* __restrict__ Wbind, const float* __restrict__ bbind,
    const float* __restrict__ Wproj, const float* __restrict__ bproj,
    float* __restrict__ out)
{
    const int W = 24, S = 8, D = 256, IN = 512, H = 512;
    __shared__ float seh[2048];
    __shared__ ushort kk[24 * 256];
    __shared__ ushort vv[24 * 256];
    __shared__ float is0s[8 * 256];
    __shared__ float sl[8 * 256];
    __shared__ float qv[8 * 256];
    __shared__ float attnw[24][8];
    __shared__ float colsum[8], mean_s[8], rstd_s[8], maskf[24];

    int nb = blockIdx.x, t = threadIdx.x;
    size_t sbase = (size_t)nb * W * IN;

    if (t < W) maskf[t] = mask[(size_t)nb * W + t] ? 0.f : -1e6f;
    for (int l = t; l < IN; l += 256) seh[l] = sent_sum[(size_t)nb * IN + l];
    __syncthreads();
    {
        float acc[S];
        #pragma unroll
        for (int j = 0; j < S; j++) acc[j] = bbind[j * D + t];
        for (int c = 0; c < IN; c++) {
            float sc = seh[c];
            #pragma unroll
            for (int j = 0; j < S; j++) acc[j] += sc * Wbind[(size_t)c * (S * D) + j * D + t];
        }
        #pragma unroll
        for (int j = 0; j < S; j++) { is0s[j * D + t] = acc[j]; sl[j * D + t] = acc[j]; }
    }
    {
        float ka[W], va[W];
        float bkv = bk[t], bvv = bv[t];
        #pragma unroll
        for (int i = 0; i < W; i++) { ka[i] = bkv; va[i] = bvv; }
        for (int ch = 0; ch < 8; ch++) {
            __syncthreads();
            for (int l = t; l < W * 64; l += 256) {
                int i = l >> 6, c = l & 63;
                seh[l] = sentence[sbase + (size_t)i * IN + ch * 64 + c];
            }
            __syncthreads();
            for (int c = 0; c < 64; c++) {
                int cg = ch * 64 + c;
                float wk = Wk[(size_t)cg * D + t];
                float wv = Wv[(size_t)cg * D + t];
                #pragma unroll
                for (int i = 0; i < W; i++) {
                    float s = seh[i * 64 + c];
                    ka[i] += s * wk; va[i] += s * wv;
                }
            }
        }
        #pragma unroll
        for (int i = 0; i < W; i++) {
            float kx = ka[i];
            kk[i * D + t] = f2bu(kx > 0.f ? kx + 1.f : expf(kx));
            vv[i * D + t] = f2bu(va[i]);
        }
    }
    __syncthreads();

    for (int it = 0; it < 3; it++) {
        {
            float qa[S]; float bqv = bq[t];
            #pragma unroll
            for (int j = 0; j < S; j++) qa[j] = bqv + is0s[j * D + t];
            for (int c = 0; c < D; c++) {
                float wq = Wq[(size_t)c * D + t];
                #pragma unroll
                for (int j = 0; j < S; j++) qa[j] += sl[j * D + c] * wq;
            }
            #pragma unroll
            for (int j = 0; j < S; j++) {
                float y = qa[j] * 0.0625f;
                qv[j * D + t] = y > 0.f ? y + 1.f : expf(y);
            }
        }
        __syncthreads();
        if (t < W * S) {
            int i = t >> 3, j = t & 7;
            float a = 0.f;
            #pragma unroll 8
            for (int d = 0; d < D; d++) a += bu2f(kk[i * D + d]) * qv[j * D + d];
            attnw[i][j] = a + maskf[i];
        }
        __syncthreads();
        if (t < W) {
            float m = attnw[t][0];
            #pragma unroll
            for (int j = 1; j < S; j++) m = fmaxf(m, attnw[t][j]);
            float e[S]; float s = 0.f;
            #pragma unroll
            for (int j = 0; j < S; j++) { e[j] = expf(attnw[t][j] - m); s += e[j]; }
            #pragma unroll
            for (int j = 0; j < S; j++) attnw[t][j] = e[j] / s + 1e-6f;
        }
        __syncthreads();
        if (t < S) {
            float s = 0.f;
            for (int i = 0; i < W; i++) s += attnw[i][t];
            colsum[t] = s;
        }
        __syncthreads();
        {
            float acc[S] = {};
            #pragma unroll
            for (int i = 0; i < W; i++) {
                float vx = bu2f(vv[i * D + t]);
                #pragma unroll
                for (int j = 0; j < S; j++) acc[j] += attnw[i][j] * vx;
            }
            #pragma unroll
            for (int j = 0; j < S; j++) qv[j * D + t] = acc[j] / colsum[j];
        }
        __syncthreads();
        {
            int lane = t & 63;
            #pragma unroll
            for (int jj = 0; jj < 2; jj++) {
                int j = (t >> 6) * 2 + jj;
                float x0 = qv[j * D + lane],       x1 = qv[j * D + lane + 64];
                float x2 = qv[j * D + lane + 128], x3 = qv[j * D + lane + 192];
                float p = x0 + x1 + x2 + x3;
                for (int off = 32; off; off >>= 1) p += __shfl_xor(p, off);
                float mean = p * (1.f / 256.f);
                float d0 = x0 - mean, d1 = x1 - mean, d2 = x2 - mean, d3 = x3 - mean;
                float vr = d0 * d0 + d1 * d1 + d2 * d2 + d3 * d3;
                for (int off = 32; off; off >>= 1) vr += __shfl_xor(vr, off);
                if (lane == 0) { mean_s[j] = mean; rstd_s[j] = rsqrtf(vr * (1.f / 256.f) + 1e-5f); }
            }
        }
        __syncthreads();
        {
            float g = g_ln[t], bb = b_ln[t];
            #pragma unroll
            for (int j = 0; j < S; j++)
                qv[j * D + t] = (qv[j * D + t] - mean_s[j]) * rstd_s[j] * g + bb;
        }
        __syncthreads();
        {
            float sa[S]; float b2v = b2[t];
            #pragma unroll
            for (int j = 0; j < S; j++) sa[j] = b2v;
            for (int half = 0; half < 2; half++) {
                int hcol = half * 256 + t;
                float ha[S]; float b1v = b1[hcol];
                #pragma unroll
                for (int j = 0; j < S; j++) ha[j] = b1v;
                for (int d = 0; d < D; d++) {
                    float w1 = W1[(size_t)d * H + hcol];
                    #pragma unroll
                    for (int j = 0; j < S; j++) ha[j] += qv[j * D + d] * w1;
                }
                __syncthreads();
                #pragma unroll
                for (int j = 0; j < S; j++) seh[j * D + t] = fmaxf(ha[j], 0.f);
                __syncthreads();
                for (int h = 0; h < 256; h++) {
                    float w2 = W2[(size_t)(half * 256 + h) * D + t];
                    #pragma unroll
                    for (int j = 0; j < S; j++) sa[j] += seh[j * D + h] * w2;
                }
            }
            __syncthreads();
            #pragma unroll
            for (int j = 0; j < S; j++) sl[j * D + t] += sa[j] * (1.f / 256.f);
        }
        __syncthreads();
    }
    {
        float oa[S]; float bpv = bproj[t];
        #pragma unroll
        for (int j = 0; j < S; j++) oa[j] = bpv;
        for (int c = 0; c < D; c++) {
            float wp1 = Wproj[(size_t)c * D + t];
            float wp2 = Wproj[(size_t)(D + c) * D + t];
            #pragma unroll
            for (int j = 0; j < S; j++)
                oa[j] += is0s[j * D + c] * wp1 + sl[j * D + c] * wp2;
        }
        #pragma unroll
        for (int j = 0; j < S; j++)
            out[(size_t)nb * (S * D) + j * D + t] = oa[j];
    }
}

extern "C" void kernel_launch(void* const* d_in, const int* in_sizes, int n_in,
                              void* d_out, int out_size, void* d_ws, size_t ws_size,
                              hipStream_t stream)
{
    const float* sentence = (const float*)d_in[0];
    const float* sent_sum = (const float*)d_in[1];
    const int*  mask      = (const int*)d_in[2];
    const float* Wk = (const float*)d_in[3];  const float* bk = (const float*)d_in[4];
    const float* Wv = (const float*)d_in[5];  const float* bv = (const float*)d_in[6];
    const float* Wq = (const float*)d_in[7];  const float* bq = (const float*)d_in[8];
    const float* g_ln = (const float*)d_in[9];  const float* b_ln = (const float*)d_in[10];
    const float* W1 = (const float*)d_in[11]; const float* b1 = (const float*)d_in[12];
    const float* W2 = (const float*)d_in[13]; const float* b2 = (const float*)d_in[14];
    const float* Wbind = (const float*)d_in[15]; const float* bbind = (const float*)d_in[16];
    const float* Wproj = (const float*)d_in[17]; const float* bproj = (const float*)d_in[18];
    float* out = (float*)d_out;

    const size_t WS_NEEDED = 139853824ULL;
    if (ws_size >= WS_NEEDED) {
        char* w = (char*)d_ws;
        float*  slots   = (float*) (w);                 // 16 MB  f32 [16384,256]
        ushort* catb    = (ushort*)(w + 16777216);      // 16 MB  bf16 [16384,512] = [is0|slots]
        ushort* kbuf    = (ushort*)(w + 33554432);      // 24 MB  [49152,256]
        ushort* vbuf    = (ushort*)(w + 58720256);      // 24 MB
        ushort* sent_bf = (ushort*)(w + 83886080);      // 48 MB  [49152,512]
        // reuse sent_bf region after kv-gemm:
        ushort* qbuf    = (ushort*)(w + 83886080);      //  8 MB
        ushort* ubuf    = (ushort*)(w + 92274688);      //  8 MB
        ushort* hbuf    = (ushort*)(w + 100663296);     // 16 MB  [16384,512]
        ushort* ssum_bf = (ushort*)(w + 134217728);     //  2 MB
        ushort* Wbind_t = (ushort*)(w + 136314880);
        ushort* Wkv_t   = (ushort*)(w + 138412032);
        ushort* Wq_t    = (ushort*)(w + 138936320);
        ushort* W1_t    = (ushort*)(w + 139067392);
        ushort* W2_t    = (ushort*)(w + 139329536);
        ushort* Wproj_t = (ushort*)(w + 139591680);

        prep_kernel<<<dim3(32512), dim3(256), 0, stream>>>(
            sentence, sent_sum, Wbind, Wk, Wv, Wq, W1, W2, Wproj,
            sent_bf, ssum_bf, Wbind_t, Wkv_t, Wq_t, W1_t, W2_t, Wproj_t);

        // is0 = ssum @ Wbind + bbind -> slots f32 + both catb halves
        mfma_gemm<GEPI_IS0, false><<<dim3(16, 16), dim3(256), 0, stream>>>(
            ssum_bf, 512, Wbind_t, bbind, nullptr,
            slots, catb, nullptr, 2048, 2048, 512);

        // k = elu(s@Wk+bk)+1 ; v = s@Wv+bv  (XCD-swizzled flat grid)
        mfma_gemm<GEPI_KV, true><<<dim3(1536), dim3(256), 0, stream>>>(
            sent_bf, 512, Wkv_t, bk, bv,
            nullptr, kbuf, vbuf, 49152, 512, 512);

        for (int it = 0; it < 3; it++) {
            mfma_gemm<GEPI_Q, false><<<dim3(2, 128), dim3(256), 0, stream>>>(
                catb + 256, 512, Wq_t, bq, nullptr,
                nullptr, qbuf, catb, 16384, 256, 256);
            attn_kernel<<<dim3(2048), dim3(256), 0, stream>>>(
                kbuf, vbuf, qbuf, mask, g_ln, b_ln, ubuf);
            mfma_gemm<GEPI_RELU, false><<<dim3(4, 128), dim3(256), 0, stream>>>(
                ubuf, 256, W1_t, b1, nullptr,
                nullptr, hbuf, nullptr, 16384, 512, 256);
            mfma_gemm<GEPI_MLP2, false><<<dim3(2, 128), dim3(256), 0, stream>>>(
                hbuf, 512, W2_t, b2, nullptr,
                slots, catb, nullptr, 16384, 256, 512);
        }

        mfma_gemm<GEPI_OUT, false><<<dim3(2, 128), dim3(256), 0, stream>>>(
            catb, 512, Wproj_t, bproj, nullptr,
            out, nullptr, nullptr, 16384, 256, 512);
    } else {
        mega_kernel<<<dim3(2048), dim3(256), 0, stream>>>(
            sentence, sent_sum, mask, Wk, bk, Wv, bv, Wq, bq, g_ln, b_ln,
            W1, b1, W2, b2, Wbind, bbind, Wproj, bproj, out);
    }
}

// Round 7
// 563.729 us; speedup vs baseline: 1.2932x; 1.2932x over previous
//
#include <hip/hip_runtime.h>
#include <hip/hip_bf16.h>
#include <math.h>

typedef unsigned int uint;
typedef unsigned short ushort;
typedef __attribute__((ext_vector_type(8))) short bf16x8;
typedef __attribute__((ext_vector_type(4))) float f32x4;

__device__ __forceinline__ float bu2f(ushort u){ union{uint u; float f;} v; v.u = ((uint)u)<<16; return v.f; }
__device__ __forceinline__ ushort f2bu(float x){ union{float f; uint u;} v; v.f = x; uint r = (v.u + 0x7FFFu + ((v.u>>16)&1u))>>16; return (ushort)r; }
__device__ __forceinline__ uint pack2(float a, float b){ return (uint)f2bu(a) | ((uint)f2bu(b) << 16); }

#define GEPI_IS0  0
#define GEPI_Q    2
#define GEPI_RELU 3
#define GEPI_MLP2 4
#define GEPI_OUT  5

// ---- small-GEMM: 64x64 tile, 4 waves (2x2) of 32x32, reg-prefetch K-loop ----
// C[M,N] = A[M,K(lda)] @ Bt[N,K]^T + bias.  High-TLP config for skinny GEMMs.
template<int EPI>
__global__ __launch_bounds__(256) void gemm64(
    const ushort* __restrict__ Abf, int lda,
    const ushort* __restrict__ Bt,
    const float* __restrict__ xb0,
    float* __restrict__ fp0,
    ushort* __restrict__ up0, ushort* __restrict__ up1,
    int M, int N, int K)
{
    __shared__ ushort As[64 * 40];
    __shared__ ushort Bs[64 * 40];
    int tid = threadIdx.x;
    int wave = tid >> 6, lane = tid & 63;
    int wr = wave >> 1, wc = wave & 1;
    int quad = lane >> 4, l15 = lane & 15;
    int row0 = blockIdx.y * 64, col0 = blockIdx.x * 64;
    int sr = tid >> 2, sc = (tid & 3) * 8;   // 64 rows x 32 cols, 16B/thread

    f32x4 acc[2][2];
    #pragma unroll
    for (int i = 0; i < 2; i++)
        #pragma unroll
        for (int j = 0; j < 2; j++) acc[i][j] = (f32x4){0.f, 0.f, 0.f, 0.f};

    const ushort* Ap = Abf + (size_t)(row0 + sr) * lda + sc;
    const ushort* Bp = Bt  + (size_t)(col0 + sr) * K   + sc;
    uint4 ra = *(const uint4*)Ap;
    uint4 rb = *(const uint4*)Bp;

    for (int k0 = 0; k0 < K; k0 += 32) {
        *(uint4*)&As[sr * 40 + sc] = ra;
        *(uint4*)&Bs[sr * 40 + sc] = rb;
        __syncthreads();
        if (k0 + 32 < K) {
            ra = *(const uint4*)(Ap + k0 + 32);
            rb = *(const uint4*)(Bp + k0 + 32);
        }
        bf16x8 af[2], bfr[2];
        #pragma unroll
        for (int mt = 0; mt < 2; mt++)
            af[mt] = *(const bf16x8*)&As[(wr * 32 + mt * 16 + l15) * 40 + quad * 8];
        #pragma unroll
        for (int nt = 0; nt < 2; nt++)
            bfr[nt] = *(const bf16x8*)&Bs[(wc * 32 + nt * 16 + l15) * 40 + quad * 8];
        #pragma unroll
        for (int mt = 0; mt < 2; mt++)
            #pragma unroll
            for (int nt = 0; nt < 2; nt++)
                acc[mt][nt] = __builtin_amdgcn_mfma_f32_16x16x32_bf16(
                    af[mt], bfr[nt], acc[mt][nt], 0, 0, 0);
        __syncthreads();
    }

    #pragma unroll
    for (int mt = 0; mt < 2; mt++) {
        #pragma unroll
        for (int nt = 0; nt < 2; nt++) {
            #pragma unroll
            for (int reg = 0; reg < 4; reg++) {
                int gr = row0 + wr * 32 + mt * 16 + quad * 4 + reg;
                int gc = col0 + wc * 32 + nt * 16 + l15;
                float x = acc[mt][nt][reg] + xb0[gc];
                if (EPI == GEPI_IS0) {
                    size_t srow = (size_t)gr * 8 + (gc >> 8);
                    int dim = gc & 255;
                    fp0[srow * 256 + dim] = x;                      // slots f32
                    ushort xb = f2bu(x);
                    up0[srow * 512 + dim]       = xb;               // catb is0
                    up0[srow * 512 + 256 + dim] = xb;               // catb slot
                } else if (EPI == GEPI_Q) {
                    float y = (x + bu2f(up1[(size_t)gr * 512 + gc])) * 0.0625f;
                    y = y > 0.f ? y + 1.f : expf(y);
                    up0[(size_t)gr * 256 + gc] = f2bu(y);           // qbuf bf16
                } else if (EPI == GEPI_RELU) {
                    up0[(size_t)gr * 512 + gc] = f2bu(fmaxf(x, 0.f)); // hbuf
                } else if (EPI == GEPI_MLP2) {
                    size_t i = (size_t)gr * 256 + gc;
                    float s = fp0[i] + x * (1.f / 256.f);
                    fp0[i] = s;                                     // slots f32
                    up0[(size_t)gr * 512 + 256 + gc] = f2bu(s);     // catb slot
                } else {  // GEPI_OUT
                    fp0[(size_t)gr * 256 + gc] = x;                 // out f32
                }
            }
        }
    }
}

// ---- KV GEMM: round-5 proven 128x128 config, f32 A inline-converted ----
__global__ __launch_bounds__(256) void gemm_kv(
    const float* __restrict__ Af32,
    const ushort* __restrict__ Bt,
    const float* __restrict__ bk, const float* __restrict__ bv,
    ushort* __restrict__ kbuf, ushort* __restrict__ vbuf, int K)
{
    __shared__ ushort As[128 * 40];
    __shared__ ushort Bs[128 * 40];
    int tid  = threadIdx.x;
    int wave = tid >> 6, lane = tid & 63;
    int wr = wave >> 1, wc = wave & 1;
    int quad = lane >> 4, l15 = lane & 15;
    int row0 = blockIdx.y * 128, col0 = blockIdx.x * 128;
    int sr = tid >> 1, sc = (tid & 1) * 16;

    f32x4 acc[4][4];
    #pragma unroll
    for (int i = 0; i < 4; i++)
        #pragma unroll
        for (int j = 0; j < 4; j++) acc[i][j] = (f32x4){0.f, 0.f, 0.f, 0.f};

    for (int k0 = 0; k0 < K; k0 += 32) {
        {
            const float* A = Af32 + (size_t)(row0 + sr) * K + k0 + sc;
            uint p[8];
            #pragma unroll
            for (int i = 0; i < 4; i++) {
                float4 f = *(const float4*)(A + i * 4);
                p[2*i]   = pack2(f.x, f.y);
                p[2*i+1] = pack2(f.z, f.w);
            }
            uint4 u0; u0.x=p[0]; u0.y=p[1]; u0.z=p[2]; u0.w=p[3];
            uint4 u1; u1.x=p[4]; u1.y=p[5]; u1.z=p[6]; u1.w=p[7];
            *(uint4*)&As[sr * 40 + sc]     = u0;
            *(uint4*)&As[sr * 40 + sc + 8] = u1;
        }
        {
            const ushort* B = Bt + (size_t)(col0 + sr) * K + k0 + sc;
            uint4 b0 = *(const uint4*)B;
            uint4 b1 = *(const uint4*)(B + 8);
            *(uint4*)&Bs[sr * 40 + sc]     = b0;
            *(uint4*)&Bs[sr * 40 + sc + 8] = b1;
        }
        __syncthreads();
        bf16x8 af[4], bfr[4];
        #pragma unroll
        for (int mt = 0; mt < 4; mt++)
            af[mt] = *(const bf16x8*)&As[(wr * 64 + mt * 16 + l15) * 40 + quad * 8];
        #pragma unroll
        for (int nt = 0; nt < 4; nt++)
            bfr[nt] = *(const bf16x8*)&Bs[(wc * 64 + nt * 16 + l15) * 40 + quad * 8];
        #pragma unroll
        for (int mt = 0; mt < 4; mt++)
            #pragma unroll
            for (int nt = 0; nt < 4; nt++)
                acc[mt][nt] = __builtin_amdgcn_mfma_f32_16x16x32_bf16(
                    af[mt], bfr[nt], acc[mt][nt], 0, 0, 0);
        __syncthreads();
    }

    #pragma unroll
    for (int mt = 0; mt < 4; mt++) {
        #pragma unroll
        for (int nt = 0; nt < 4; nt++) {
            #pragma unroll
            for (int reg = 0; reg < 4; reg++) {
                int gr = row0 + wr * 64 + mt * 16 + quad * 4 + reg;
                int gc = col0 + wc * 64 + nt * 16 + l15;
                float x = acc[mt][nt][reg];
                if (gc < 256) {
                    x += bk[gc];
                    x = x > 0.f ? x + 1.f : expf(x);
                    kbuf[(size_t)gr * 256 + gc] = f2bu(x);
                } else {
                    x += bv[gc - 256];
                    vbuf[(size_t)gr * 256 + gc - 256] = f2bu(x);
                }
            }
        }
    }
}

// ssum -> bf16 + weights f32 -> bf16 transposed [N][K].
__global__ __launch_bounds__(256) void prep_kernel(
    const float* __restrict__ sent_sum,
    const float* __restrict__ Wbind, const float* __restrict__ Wk,
    const float* __restrict__ Wv, const float* __restrict__ Wq,
    const float* __restrict__ W1, const float* __restrict__ W2,
    const float* __restrict__ Wproj,
    ushort* __restrict__ ssum_bf,
    ushort* __restrict__ Wbind_t, ushort* __restrict__ Wkv_t,
    ushort* __restrict__ Wq_t, ushort* __restrict__ W1_t,
    ushort* __restrict__ W2_t, ushort* __restrict__ Wproj_t)
{
    int gid = blockIdx.x * 256 + threadIdx.x;
    if (gid < 262144) {            // sent_sum: 1,048,576 f32 as vec4
        float4 f = ((const float4*)sent_sum)[gid];
        uint2 o; o.x = pack2(f.x, f.y); o.y = pack2(f.z, f.w);
        ((uint2*)ssum_bf)[gid] = o; return;
    }
    int idx = gid - 262144;
    if (idx < 1048576) { int n = idx >> 9, k = idx & 511;
        Wbind_t[idx] = f2bu(Wbind[(size_t)k * 2048 + n]); return; }
    idx -= 1048576;
    if (idx < 262144) { int n = idx >> 9, k = idx & 511;
        Wkv_t[idx] = f2bu(n < 256 ? Wk[(size_t)k * 256 + n] : Wv[(size_t)k * 256 + n - 256]); return; }
    idx -= 262144;
    if (idx < 65536) { int n = idx >> 8, k = idx & 255;
        Wq_t[idx] = f2bu(Wq[(size_t)k * 256 + n]); return; }
    idx -= 65536;
    if (idx < 131072) { int n = idx >> 8, k = idx & 255;
        W1_t[idx] = f2bu(W1[(size_t)k * 512 + n]); return; }
    idx -= 131072;
    if (idx < 131072) { int n = idx >> 9, k = idx & 511;
        W2_t[idx] = f2bu(W2[(size_t)k * 256 + n]); return; }
    idx -= 131072;
    if (idx < 131072) { int n = idx >> 9, k = idx & 511;
        Wproj_t[idx] = f2bu(Wproj[(size_t)k * 256 + n]); return; }
}

// Per-(n,b): logits -> softmax(+eps) -> word renorm -> update -> LayerNorm.
__global__ __launch_bounds__(256) void attn_kernel(
    const ushort* __restrict__ kbuf, const ushort* __restrict__ vbuf,
    const ushort* __restrict__ qbuf, const int* __restrict__ mask,
    const float* __restrict__ g_ln, const float* __restrict__ b_ln,
    ushort* __restrict__ ubuf)
{
    const int W = 24, S = 8;
    __shared__ ushort kk[24 * 256], vv[24 * 256];
    __shared__ float qs[8 * 257], us[8 * 257];
    __shared__ float attnw[24][8];
    __shared__ float colsum[8], mean_s[8], rstd_s[8], maskf[24];

    int nb = blockIdx.x, t = threadIdx.x;
    size_t bw = (size_t)nb * W * 256, bs = (size_t)nb * S * 256;

    for (int l = t; l < 3072; l += 256) {
        ((uint*)kk)[l] = ((const uint*)(kbuf + bw))[l];
        ((uint*)vv)[l] = ((const uint*)(vbuf + bw))[l];
    }
    for (int l = t; l < 2048; l += 256)
        qs[(l >> 8) * 257 + (l & 255)] = bu2f(qbuf[bs + l]);
    if (t < W) maskf[t] = mask[(size_t)nb * W + t] ? 0.f : -1e6f;
    __syncthreads();

    if (t < W * S) {
        int i = t >> 3, j = t & 7;
        float a = 0.f;
        #pragma unroll 8
        for (int d = 0; d < 256; d++) a += bu2f(kk[i * 256 + d]) * qs[j * 257 + d];
        attnw[i][j] = a + maskf[i];
    }
    __syncthreads();

    if (t < W) {
        float m = attnw[t][0];
        #pragma unroll
        for (int j = 1; j < S; j++) m = fmaxf(m, attnw[t][j]);
        float e[S]; float s = 0.f;
        #pragma unroll
        for (int j = 0; j < S; j++) { e[j] = expf(attnw[t][j] - m); s += e[j]; }
        #pragma unroll
        for (int j = 0; j < S; j++) attnw[t][j] = e[j] / s + 1e-6f;
    }
    __syncthreads();

    if (t < S) {
        float s = 0.f;
        for (int i = 0; i < W; i++) s += attnw[i][t];
        colsum[t] = s;
    }
    __syncthreads();

    {
        float acc[S] = {};
        #pragma unroll
        for (int i = 0; i < W; i++) {
            float vx = bu2f(vv[i * 256 + t]);
            #pragma unroll
            for (int j = 0; j < S; j++) acc[j] += attnw[i][j] * vx;
        }
        #pragma unroll
        for (int j = 0; j < S; j++) us[j * 257 + t] = acc[j] / colsum[j];
    }
    __syncthreads();

    {
        int lane = t & 63;
        #pragma unroll
        for (int jj = 0; jj < 2; jj++) {
            int j = (t >> 6) * 2 + jj;
            float x0 = us[j * 257 + lane],       x1 = us[j * 257 + lane + 64];
            float x2 = us[j * 257 + lane + 128], x3 = us[j * 257 + lane + 192];
            float p = x0 + x1 + x2 + x3;
            for (int off = 32; off; off >>= 1) p += __shfl_xor(p, off);
            float mean = p * (1.f / 256.f);
            float d0 = x0 - mean, d1 = x1 - mean, d2 = x2 - mean, d3 = x3 - mean;
            float vr = d0 * d0 + d1 * d1 + d2 * d2 + d3 * d3;
            for (int off = 32; off; off >>= 1) vr += __shfl_xor(vr, off);
            if (lane == 0) {
                mean_s[j] = mean;
                rstd_s[j] = rsqrtf(vr * (1.f / 256.f) + 1e-5f);
            }
        }
    }
    __syncthreads();

    {
        float g = g_ln[t], bb = b_ln[t];
        #pragma unroll
        for (int j = 0; j < S; j++)
            ubuf[bs + j * 256 + t] = f2bu((us[j * 257 + t] - mean_s[j]) * rstd_s[j] * g + bb);
    }
}

// ---------------- fallback: round-4 proven mega-kernel ----------------
__global__ __launch_bounds__(256) void mega_kernel(
    const float* __restrict__ sentence, const float* __restrict__ sent_sum,
    const int*  __restrict__ mask,
    const float* __restrict__ Wk, const float* __restrict__ bk,
    const float* __restrict__ Wv, const float* __restrict__ bv,
    const float* __restrict__ Wq, const float* __restrict__ bq,
    const float* __restrict__ g_ln, const float* __restrict__ b_ln,
    const float* __restrict__ W1, const float* __restrict__ b1,
    const float* __restrict__ W2, const float* __restrict__ b2,
    const float* __restrict__ Wbind, const float* __restrict__ bbind,
    const float* __restrict__ Wproj, const float* __restrict__ bproj,
    float* __restrict__ out)
{
    const int W = 24, S = 8, D = 256, IN = 512, H = 512;
    __shared__ float seh[2048];
    __shared__ ushort kk[24 * 256];
    __shared__ ushort vv[24 * 256];
    __shared__ float is0s[8 * 256];
    __shared__ float sl[8 * 256];
    __shared__ float qv[8 * 256];
    __shared__ float attnw[24][8];
    __shared__ float colsum[8], mean_s[8], rstd_s[8], maskf[24];

    int nb = blockIdx.x, t = threadIdx.x;
    size_t sbase = (size_t)nb * W * IN;

    if (t < W) maskf[t] = mask[(size_t)nb * W + t] ? 0.f : -1e6f;
    for (int l = t; l < IN; l += 256) seh[l] = sent_sum[(size_t)nb * IN + l];
    __syncthreads();
    {
        float acc[S];
        #pragma unroll
        for (int j = 0; j < S; j++) acc[j] = bbind[j * D + t];
        for (int c = 0; c < IN; c++) {
            float sc = seh[c];
            #pragma unroll
            for (int j = 0; j < S; j++) acc[j] += sc * Wbind[(size_t)c * (S * D) + j * D + t];
        }
        #pragma unroll
        for (int j = 0; j < S; j++) { is0s[j * D + t] = acc[j]; sl[j * D + t] = acc[j]; }
    }
    {
        float ka[W], va[W];
        float bkv = bk[t], bvv = bv[t];
        #pragma unroll
        for (int i = 0; i < W; i++) { ka[i] = bkv; va[i] = bvv; }
        for (int ch = 0; ch < 8; ch++) {
            __syncthreads();
            for (int l = t; l < W * 64; l += 256) {
                int i = l >> 6, c = l & 63;
                seh[l] = sentence[sbase + (size_t)i * IN + ch * 64 + c];
            }
            __syncthreads();
            for (int c = 0; c < 64; c++) {
                int cg = ch * 64 + c;
                float wk = Wk[(size_t)cg * D + t];
                float wv = Wv[(size_t)cg * D + t];
                #pragma unroll
                for (int i = 0; i < W; i++) {
                    float s = seh[i * 64 + c];
                    ka[i] += s * wk; va[i] += s * wv;
                }
            }
        }
        #pragma unroll
        for (int i = 0; i < W; i++) {
            float kx = ka[i];
            kk[i * D + t] = f2bu(kx > 0.f ? kx + 1.f : expf(kx));
            vv[i * D + t] = f2bu(va[i]);
        }
    }
    __syncthreads();

    for (int it = 0; it < 3; it++) {
        {
            float qa[S]; float bqv = bq[t];
            #pragma unroll
            for (int j = 0; j < S; j++) qa[j] = bqv + is0s[j * D + t];
            for (int c = 0; c < D; c++) {
                float wq = Wq[(size_t)c * D + t];
                #pragma unroll
                for (int j = 0; j < S; j++) qa[j] += sl[j * D + c] * wq;
            }
            #pragma unroll
            for (int j = 0; j < S; j++) {
                float y = qa[j] * 0.0625f;
                qv[j * D + t] = y > 0.f ? y + 1.f : expf(y);
            }
        }
        __syncthreads();
        if (t < W * S) {
            int i = t >> 3, j = t & 7;
            float a = 0.f;
            #pragma unroll 8
            for (int d = 0; d < D; d++) a += bu2f(kk[i * D + d]) * qv[j * D + d];
            attnw[i][j] = a + maskf[i];
        }
        __syncthreads();
        if (t < W) {
            float m = attnw[t][0];
            #pragma unroll
            for (int j = 1; j < S; j++) m = fmaxf(m, attnw[t][j]);
            float e[S]; float s = 0.f;
            #pragma unroll
            for (int j = 0; j < S; j++) { e[j] = expf(attnw[t][j] - m); s += e[j]; }
            #pragma unroll
            for (int j = 0; j < S; j++) attnw[t][j] = e[j] / s + 1e-6f;
        }
        __syncthreads();
        if (t < S) {
            float s = 0.f;
            for (int i = 0; i < W; i++) s += attnw[i][t];
            colsum[t] = s;
        }
        __syncthreads();
        {
            float acc[S] = {};
            #pragma unroll
            for (int i = 0; i < W; i++) {
                float vx = bu2f(vv[i * D + t]);
                #pragma unroll
                for (int j = 0; j < S; j++) acc[j] += attnw[i][j] * vx;
            }
            #pragma unroll
            for (int j = 0; j < S; j++) qv[j * D + t] = acc[j] / colsum[j];
        }
        __syncthreads();
        {
            int lane = t & 63;
            #pragma unroll
            for (int jj = 0; jj < 2; jj++) {
                int j = (t >> 6) * 2 + jj;
                float x0 = qv[j * D + lane],       x1 = qv[j * D + lane + 64];
                float x2 = qv[j * D + lane + 128], x3 = qv[j * D + lane + 192];
                float p = x0 + x1 + x2 + x3;
                for (int off = 32; off; off >>= 1) p += __shfl_xor(p, off);
                float mean = p * (1.f / 256.f);
                float d0 = x0 - mean, d1 = x1 - mean, d2 = x2 - mean, d3 = x3 - mean;
                float vr = d0 * d0 + d1 * d1 + d2 * d2 + d3 * d3;
                for (int off = 32; off; off >>= 1) vr += __shfl_xor(vr, off);
                if (lane == 0) { mean_s[j] = mean; rstd_s[j] = rsqrtf(vr * (1.f / 256.f) + 1e-5f); }
            }
        }
        __syncthreads();
        {
            float g = g_ln[t], bb = b_ln[t];
            #pragma unroll
            for (int j = 0; j < S; j++)
                qv[j * D + t] = (qv[j * D + t] - mean_s[j]) * rstd_s[j] * g + bb;
        }
        __syncthreads();
        {
            float sa[S]; float b2v = b2[t];
            #pragma unroll
            for (int j = 0; j < S; j++) sa[j] = b2v;
            for (int half = 0; half < 2; half++) {
                int hcol = half * 256 + t;
                float ha[S]; float b1v = b1[hcol];
                #pragma unroll
                for (int j = 0; j < S; j++) ha[j] = b1v;
                for (int d = 0; d < D; d++) {
                    float w1 = W1[(size_t)d * H + hcol];
                    #pragma unroll
                    for (int j = 0; j < S; j++) ha[j] += qv[j * D + d] * w1;
                }
                __syncthreads();
                #pragma unroll
                for (int j = 0; j < S; j++) seh[j * D + t] = fmaxf(ha[j], 0.f);
                __syncthreads();
                for (int h = 0; h < 256; h++) {
                    float w2 = W2[(size_t)(half * 256 + h) * D + t];
                    #pragma unroll
                    for (int j = 0; j < S; j++) sa[j] += seh[j * D + h] * w2;
                }
            }
            __syncthreads();
            #pragma unroll
            for (int j = 0; j < S; j++) sl[j * D + t] += sa[j] * (1.f / 256.f);
        }
        __syncthreads();
    }
    {
        float oa[S]; float bpv = bproj[t];
        #pragma unroll
        for (int j = 0; j < S; j++) oa[j] = bpv;
        for (int c = 0; c < D; c++) {
            float wp1 = Wproj[(size_t)c * D + t];
            float wp2 = Wproj[(size_t)(D + c) * D + t];
            #pragma unroll
            for (int j = 0; j < S; j++)
                oa[j] += is0s[j * D + c] * wp1 + sl[j * D + c] * wp2;
        }
        #pragma unroll
        for (int j = 0; j < S; j++)
            out[(size_t)nb * (S * D) + j * D + t] = oa[j];
    }
}

extern "C" void kernel_launch(void* const* d_in, const int* in_sizes, int n_in,
                              void* d_out, int out_size, void* d_ws, size_t ws_size,
                              hipStream_t stream)
{
    const float* sentence = (const float*)d_in[0];
    const float* sent_sum = (const float*)d_in[1];
    const int*  mask      = (const int*)d_in[2];
    const float* Wk = (const float*)d_in[3];  const float* bk = (const float*)d_in[4];
    const float* Wv = (const float*)d_in[5];  const float* bv = (const float*)d_in[6];
    const float* Wq = (const float*)d_in[7];  const float* bq = (const float*)d_in[8];
    const float* g_ln = (const float*)d_in[9];  const float* b_ln = (const float*)d_in[10];
    const float* W1 = (const float*)d_in[11]; const float* b1 = (const float*)d_in[12];
    const float* W2 = (const float*)d_in[13]; const float* b2 = (const float*)d_in[14];
    const float* Wbind = (const float*)d_in[15]; const float* bbind = (const float*)d_in[16];
    const float* Wproj = (const float*)d_in[17]; const float* bproj = (const float*)d_in[18];
    float* out = (float*)d_out;

    const size_t WS_NEEDED = 123076608ULL;
    if (ws_size >= WS_NEEDED) {
        char* w = (char*)d_ws;
        float*  slots   = (float*) (w);                 // 16 MB  [16384,256] f32
        ushort* catb    = (ushort*)(w + 16777216);      // 16 MB  [16384,512] = [is0|slots] bf16
        ushort* kbuf    = (ushort*)(w + 33554432);      // 24 MB  [49152,256]
        ushort* vbuf    = (ushort*)(w + 58720256);      // 24 MB
        ushort* qbuf    = (ushort*)(w + 83886080);      //  8 MB
        ushort* ubuf    = (ushort*)(w + 92274688);      //  8 MB
        ushort* hbuf    = (ushort*)(w + 100663296);     // 16 MB  [16384,512]
        ushort* ssum_bf = (ushort*)(w + 117440512);     //  2 MB
        ushort* Wbind_t = (ushort*)(w + 119537664);
        ushort* Wkv_t   = (ushort*)(w + 121634816);
        ushort* Wq_t    = (ushort*)(w + 122159104);
        ushort* W1_t    = (ushort*)(w + 122290176);
        ushort* W2_t    = (ushort*)(w + 122552320);
        ushort* Wproj_t = (ushort*)(w + 122814464);

        prep_kernel<<<dim3(7936), dim3(256), 0, stream>>>(
            sent_sum, Wbind, Wk, Wv, Wq, W1, W2, Wproj,
            ssum_bf, Wbind_t, Wkv_t, Wq_t, W1_t, W2_t, Wproj_t);

        // is0 = ssum @ Wbind + bbind -> slots f32 + both catb halves
        gemm64<GEPI_IS0><<<dim3(32, 32), dim3(256), 0, stream>>>(
            ssum_bf, 512, Wbind_t, bbind,
            slots, catb, nullptr, 2048, 2048, 512);

        // k = elu(s@Wk+bk)+1 ; v = s@Wv+bv  (round-5 proven config)
        gemm_kv<<<dim3(4, 384), dim3(256), 0, stream>>>(
            sentence, Wkv_t, bk, bv, kbuf, vbuf, 512);

        for (int it = 0; it < 3; it++) {
            gemm64<GEPI_Q><<<dim3(4, 256), dim3(256), 0, stream>>>(
                catb + 256, 512, Wq_t, bq,
                nullptr, qbuf, catb, 16384, 256, 256);
            attn_kernel<<<dim3(2048), dim3(256), 0, stream>>>(
                kbuf, vbuf, qbuf, mask, g_ln, b_ln, ubuf);
            gemm64<GEPI_RELU><<<dim3(8, 256), dim3(256), 0, stream>>>(
                ubuf, 256, W1_t, b1,
                nullptr, hbuf, nullptr, 16384, 512, 256);
            gemm64<GEPI_MLP2><<<dim3(4, 256), dim3(256), 0, stream>>>(
                hbuf, 512, W2_t, b2,
                slots, catb, nullptr, 16384, 256, 512);
        }

        gemm64<GEPI_OUT><<<dim3(4, 256), dim3(256), 0, stream>>>(
            catb, 512, Wproj_t, bproj,
            out, nullptr, nullptr, 16384, 256, 512);
    } else {
        mega_kernel<<<dim3(2048), dim3(256), 0, stream>>>(
            sentence, sent_sum, mask, Wk, bk, Wv, bv, Wq, bq, g_ln, b_ln,
            W1, b1, W2, b2, Wbind, bbind, Wproj, bproj, out);
    }
}